// Round 1
// baseline (985.267 us; speedup 1.0000x reference)
//
#include <hip/hip_runtime.h>
#include <stdint.h>

#define NTOK 8192
#define H_ 1024
#define F_ 4096
#define E_ 8
#define ROWS_CAP 17408   // 16384 slots + up to 8*128 padding
#define MBLK 136         // ROWS_CAP/128

using f32x4  = __attribute__((ext_vector_type(4))) float;
using short8 = __attribute__((ext_vector_type(8))) short;

__device__ __forceinline__ ushort f2bf(float f) {
  union { float f; uint32_t u; } v; v.f = f;
  uint32_t r = (v.u + 0x7FFFu + ((v.u >> 16) & 1u)) >> 16;
  return (ushort)r;
}

// ---------------- init: zero counts/cursors, invalidate token list ----------
__global__ void k_init(int* cnt, int* cur, int* tok, float* wl) {
  int i = blockIdx.x * 256 + threadIdx.x;
  if (i < E_) { cnt[i] = 0; cur[i] = 0; }
  if (i < ROWS_CAP) { tok[i] = -1; wl[i] = 0.f; }
}

// ---------------- transpose + fp32->bf16 convert: W[E][R][C] -> WT[E][C][R] --
__global__ __launch_bounds__(256) void k_transcvt(const float* __restrict__ W,
                                                  ushort* __restrict__ WT,
                                                  int R, int C) {
  __shared__ float t[64][65];
  int e = blockIdx.z;
  int c0 = blockIdx.x * 64, r0 = blockIdx.y * 64;
  const float* Wp = W + (size_t)e * R * C;
  ushort* Tp = WT + (size_t)e * R * C;
  int tx = threadIdx.x & 15, ty = threadIdx.x >> 4;
#pragma unroll
  for (int i = 0; i < 4; i++) {
    int lr = ty + i * 16;
    const float4 v = *(const float4*)&Wp[(size_t)(r0 + lr) * C + c0 + tx * 4];
    t[lr][tx * 4 + 0] = v.x; t[lr][tx * 4 + 1] = v.y;
    t[lr][tx * 4 + 2] = v.z; t[lr][tx * 4 + 3] = v.w;
  }
  __syncthreads();
#pragma unroll
  for (int i = 0; i < 4; i++) {
    int lc = ty + i * 16;                 // output row = original col
    ushort4 o;
    o.x = f2bf(t[tx * 4 + 0][lc]);
    o.y = f2bf(t[tx * 4 + 1][lc]);
    o.z = f2bf(t[tx * 4 + 2][lc]);
    o.w = f2bf(t[tx * 4 + 3][lc]);
    *(ushort4*)&Tp[(size_t)(c0 + lc) * R + r0 + tx * 4] = o;
  }
}

// ---------------- router: fp64 scores, softmax, top-2 ------------------------
__global__ __launch_bounds__(256) void k_router(const float* __restrict__ x,
                                                const float* __restrict__ Wr,
                                                const float* __restrict__ br,
                                                const float* __restrict__ bbuf,
                                                int* cnt, int* te, float* tw) {
  int wid = threadIdx.x >> 6, lane = threadIdx.x & 63;
  int t = blockIdx.x * 4 + wid;
  const float* xp = x + (size_t)t * H_;
  double acc[E_];
#pragma unroll
  for (int e = 0; e < E_; e++) acc[e] = 0.0;
  for (int j = lane; j < H_; j += 64) {
    float xv = xp[j];
    const float4 w0 = *(const float4*)&Wr[j * 8];
    const float4 w1 = *(const float4*)&Wr[j * 8 + 4];
    acc[0] += (double)xv * (double)w0.x;
    acc[1] += (double)xv * (double)w0.y;
    acc[2] += (double)xv * (double)w0.z;
    acc[3] += (double)xv * (double)w0.w;
    acc[4] += (double)xv * (double)w1.x;
    acc[5] += (double)xv * (double)w1.y;
    acc[6] += (double)xv * (double)w1.z;
    acc[7] += (double)xv * (double)w1.w;
  }
#pragma unroll
  for (int e = 0; e < E_; e++)
    for (int s = 32; s > 0; s >>= 1) acc[e] += __shfl_xor(acc[e], s);
  if (lane == 0) {
    double s[E_], m = -1e300;
    for (int e = 0; e < E_; e++) { s[e] = acc[e] + (double)br[e]; if (s[e] > m) m = s[e]; }
    double pe[E_], sum = 0.0;
    for (int e = 0; e < E_; e++) { pe[e] = exp(s[e] - m); sum += pe[e]; }
    double pr[E_], bb[E_];
    for (int e = 0; e < E_; e++) { pr[e] = pe[e] / sum; bb[e] = pr[e] + (double)bbuf[e]; }
    int e0 = 0;
    for (int e = 1; e < E_; e++) if (bb[e] > bb[e0]) e0 = e;
    int e1 = (e0 == 0) ? 1 : 0;
    for (int e = 0; e < E_; e++) if (e != e0 && bb[e] > bb[e1]) e1 = e;
    int a0 = 0;
    for (int e = 1; e < E_; e++) if (pr[e] > pr[a0]) a0 = e;
    int a1 = (a0 == 0) ? 1 : 0;
    for (int e = 0; e < E_; e++) if (e != a0 && pr[e] > pr[a1]) a1 = e;
    double iv = 1.0 / (pr[a0] + pr[a1]);
    te[t * 2] = e0; te[t * 2 + 1] = e1;
    tw[t * 2] = (float)(pr[a0] * iv); tw[t * 2 + 1] = (float)(pr[a1] * iv);
    atomicAdd(&cnt[e0], 1); atomicAdd(&cnt[e1], 1);
  }
}

// ---------------- offsets: pad each expert's region to multiple of 128 -------
__global__ void k_offsets(const int* cnt, int* off) {
  if (threadIdx.x == 0 && blockIdx.x == 0) {
    int o = 0; off[0] = 0;
    for (int e = 0; e < E_; e++) { o += ((cnt[e] + 127) >> 7) << 7; off[e + 1] = o; }
  }
}

// ---------------- build per-expert token lists -------------------------------
__global__ void k_build(const int* __restrict__ te, const float* __restrict__ tw,
                        const int* __restrict__ off, int* cur, int* tok, float* wl) {
  int t = blockIdx.x * 256 + threadIdx.x;
  if (t >= NTOK) return;
#pragma unroll
  for (int s = 0; s < 2; s++) {
    int e = te[t * 2 + s];
    int slot = atomicAdd(&cur[e], 1);
    int pos = off[e] + slot;
    tok[pos] = t; wl[pos] = tw[t * 2 + s];
  }
}

// ---------------- gather x rows -> bf16 compacted ----------------------------
__global__ __launch_bounds__(256) void k_gather(const float* __restrict__ x,
                                                const int* __restrict__ tok,
                                                ushort* __restrict__ Xg) {
  int row = blockIdx.x;
  int t = tok[row];
  if (t < 0) return;
  const float4* src = (const float4*)(x + (size_t)t * H_);
  ushort4* dst = (ushort4*)(Xg + (size_t)row * H_);
  int i = threadIdx.x;   // 256 threads * 4 floats = 1024
  float4 v = src[i];
  ushort4 o; o.x = f2bf(v.x); o.y = f2bf(v.y); o.z = f2bf(v.z); o.w = f2bf(v.w);
  dst[i] = o;
}

// ---------------- zero output ------------------------------------------------
__global__ void k_zero(float* out) {
  size_t i = (size_t)blockIdx.x * 256 + threadIdx.x;
  float4 z; z.x = 0.f; z.y = 0.f; z.z = 0.f; z.w = 0.f;
  ((float4*)out)[i] = z;
}

// ---------------- tiled bf16 MFMA GEMM --------------------------------------
// A [rows][K] bf16 row-major; BT [E][N][K] bf16 (k-contiguous).
// MODE 0: C = gelu(A@B + b1[e]) -> Cbf (bf16 [rows][N])
// MODE 1: atomicAdd(Out[tok[r]][c], wl[r] * (A@B + b2[e]))
template <int MODE>
__global__ __launch_bounds__(256) void k_gemm(const ushort* __restrict__ A,
                                              const ushort* __restrict__ BT,
                                              const float* __restrict__ bias,
                                              ushort* __restrict__ Cbf,
                                              float* __restrict__ Out,
                                              const int* __restrict__ off,
                                              const int* __restrict__ tok,
                                              const float* __restrict__ wl,
                                              int K, int N) {
  int row0 = blockIdx.y * 128;
  int lastoff = off[E_];
  if (row0 >= lastoff) return;
  int e = 0;
  while (off[e + 1] <= row0) e++;
  int n0 = blockIdx.x * 128;
  const ushort* Bp = BT + (size_t)e * (size_t)N * (size_t)K;

  __shared__ __align__(16) ushort As[128 * 32];
  __shared__ __align__(16) ushort Bs[128 * 32];

  int tid = threadIdx.x, lane = tid & 63, wid = tid >> 6;
  int wr = wid >> 1, wc = wid & 1;

  f32x4 acc[4][4];
#pragma unroll
  for (int m = 0; m < 4; m++)
#pragma unroll
    for (int n = 0; n < 4; n++) acc[m][n] = (f32x4){0.f, 0.f, 0.f, 0.f};

  int srow = tid >> 1;            // 0..127
  int skh = (tid & 1) * 16;       // 0 or 16 (k offset, 16 elems = 32B)
  const size_t aRowBase = (size_t)(row0 + srow) * (size_t)K + skh;
  const size_t bRowBase = (size_t)(n0 + srow) * (size_t)K + skh;
  int ldsOff = srow * 32 + skh;

  int fr = lane & 15, fq = lane >> 4;   // fragment row/col-in-16, k-group
  int aOff0 = (wr * 64 + fr) * 32 + fq * 8;
  int bOff0 = (wc * 64 + fr) * 32 + fq * 8;

  int nk = K >> 5;
  for (int kk = 0; kk < nk; kk++) {
    int k0 = kk << 5;
    uint4 a0 = *(const uint4*)&A[aRowBase + k0];
    uint4 a1 = *(const uint4*)&A[aRowBase + k0 + 8];
    uint4 b0 = *(const uint4*)&Bp[bRowBase + k0];
    uint4 b1 = *(const uint4*)&Bp[bRowBase + k0 + 8];
    __syncthreads();
    *(uint4*)&As[ldsOff] = a0;
    *(uint4*)&As[ldsOff + 8] = a1;
    *(uint4*)&Bs[ldsOff] = b0;
    *(uint4*)&Bs[ldsOff + 8] = b1;
    __syncthreads();
    short8 af[4], bfr[4];
#pragma unroll
    for (int m = 0; m < 4; m++) af[m] = *(const short8*)&As[aOff0 + m * 16 * 32];
#pragma unroll
    for (int n = 0; n < 4; n++) bfr[n] = *(const short8*)&Bs[bOff0 + n * 16 * 32];
#pragma unroll
    for (int m = 0; m < 4; m++)
#pragma unroll
      for (int n = 0; n < 4; n++)
        acc[m][n] = __builtin_amdgcn_mfma_f32_16x16x32_bf16(af[m], bfr[n], acc[m][n], 0, 0, 0);
  }

  const float* bp = bias + (size_t)e * N;
  if (MODE == 0) {
#pragma unroll
    for (int m = 0; m < 4; m++)
#pragma unroll
      for (int n = 0; n < 4; n++)
#pragma unroll
        for (int j = 0; j < 4; j++) {
          int r = row0 + wr * 64 + m * 16 + (fq << 2) + j;
          int c = n0 + wc * 64 + n * 16 + fr;
          float v = acc[m][n][j] + bp[c];
          v = 0.5f * v * (1.0f + erff(v * 0.70710678118654752f));
          Cbf[(size_t)r * (size_t)N + c] = f2bf(v);
        }
  } else {
#pragma unroll
    for (int m = 0; m < 4; m++)
#pragma unroll
      for (int j = 0; j < 4; j++) {
        int r = row0 + wr * 64 + m * 16 + (fq << 2) + j;
        int t = tok[r];
        if (t < 0) continue;
        float w = wl[r];
#pragma unroll
        for (int n = 0; n < 4; n++) {
          int c = n0 + wc * 64 + n * 16 + fr;
          atomicAdd(&Out[(size_t)t * (size_t)N + c], w * (acc[m][n][j] + bp[c]));
        }
      }
  }
}

extern "C" void kernel_launch(void* const* d_in, const int* in_sizes, int n_in,
                              void* d_out, int out_size, void* d_ws, size_t ws_size,
                              hipStream_t stream) {
  (void)in_sizes; (void)n_in; (void)out_size; (void)ws_size;
  const float* x    = (const float*)d_in[0];
  const float* bbuf = (const float*)d_in[1];
  const float* Wr   = (const float*)d_in[2];
  const float* br   = (const float*)d_in[3];
  const float* W1   = (const float*)d_in[4];
  const float* b1   = (const float*)d_in[5];
  const float* W2   = (const float*)d_in[6];
  const float* b2   = (const float*)d_in[7];
  float* out = (float*)d_out;

  char* ws = (char*)d_ws;
  ushort* W1T = (ushort*)ws;                         // [E][F][H] bf16: 67108864 B
  ushort* W2T = (ushort*)(ws + 67108864);            // [E][H][F] bf16: 67108864 B
  ushort* Xg  = (ushort*)(ws + 134217728);           // [ROWS_CAP][H] bf16
  ushort* h1  = (ushort*)(ws + 169869312);           // [ROWS_CAP][F] bf16
  char* meta  = ws + 312475648;
  int*   cnt = (int*)(meta);
  int*   off = (int*)(meta + 64);
  int*   cur = (int*)(meta + 128);
  int*   te  = (int*)(meta + 256);                   // [NTOK*2]
  float* tw  = (float*)(meta + 256 + 65536);         // [NTOK*2]
  int*   tok = (int*)(meta + 256 + 131072);          // [ROWS_CAP]
  float* wl  = (float*)(meta + 256 + 131072 + 69632);// [ROWS_CAP]

  k_init<<<ROWS_CAP / 256, 256, 0, stream>>>(cnt, cur, tok, wl);
  k_transcvt<<<dim3(F_ / 64, H_ / 64, E_), 256, 0, stream>>>(W1, W1T, H_, F_);
  k_transcvt<<<dim3(H_ / 64, F_ / 64, E_), 256, 0, stream>>>(W2, W2T, F_, H_);
  k_router<<<NTOK / 4, 256, 0, stream>>>(x, Wr, br, bbuf, cnt, te, tw);
  k_offsets<<<1, 64, 0, stream>>>(cnt, off);
  k_build<<<NTOK / 256, 256, 0, stream>>>(te, tw, off, cur, tok, wl);
  k_gather<<<ROWS_CAP, 256, 0, stream>>>(x, tok, Xg);
  k_zero<<<(NTOK * H_ / 4) / 256, 256, 0, stream>>>(out);
  k_gemm<0><<<dim3(F_ / 128, MBLK), 256, 0, stream>>>(Xg, W1T, b1, h1, nullptr, off, nullptr, nullptr, H_, F_);
  k_gemm<1><<<dim3(H_ / 128, MBLK), 256, 0, stream>>>(h1, W2T, b2, nullptr, out, off, tok, wl, F_, H_);
}

// Round 2
// 934.670 us; speedup vs baseline: 1.0541x; 1.0541x over previous
//
#include <hip/hip_runtime.h>
#include <stdint.h>

#define NTOK 8192
#define H_ 1024
#define F_ 4096
#define E_ 8
#define ROWS_CAP 17408   // 16384 slots + up to 8*128 padding
#define MBLK 136         // ROWS_CAP/128

using f32x4  = __attribute__((ext_vector_type(4))) float;
using short8 = __attribute__((ext_vector_type(8))) short;

typedef __attribute__((address_space(1))) const uint32_t gu32;
typedef __attribute__((address_space(3))) uint32_t lu32;

__device__ __forceinline__ void glds16(const void* g, void* l) {
  __builtin_amdgcn_global_load_lds((gu32*)g, (lu32*)l, 16, 0, 0);
}

__device__ __forceinline__ ushort f2bf(float f) {
  union { float f; uint32_t u; } v; v.f = f;
  uint32_t r = (v.u + 0x7FFFu + ((v.u >> 16) & 1u)) >> 16;
  return (ushort)r;
}

// ---------------- init: zero counts/cursors, invalidate token list ----------
__global__ void k_init(int* cnt, int* cur, int* tok, float* wl) {
  int i = blockIdx.x * 256 + threadIdx.x;
  if (i < E_) { cnt[i] = 0; cur[i] = 0; }
  if (i < ROWS_CAP) { tok[i] = -1; wl[i] = 0.f; }
}

// ---------------- transpose + fp32->bf16 convert: W[E][R][C] -> WT[E][C][R] --
__global__ __launch_bounds__(256) void k_transcvt(const float* __restrict__ W,
                                                  ushort* __restrict__ WT,
                                                  int R, int C) {
  __shared__ float t[64][65];
  int e = blockIdx.z;
  int c0 = blockIdx.x * 64, r0 = blockIdx.y * 64;
  const float* Wp = W + (size_t)e * R * C;
  ushort* Tp = WT + (size_t)e * R * C;
  int tx = threadIdx.x & 15, ty = threadIdx.x >> 4;
#pragma unroll
  for (int i = 0; i < 4; i++) {
    int lr = ty + i * 16;
    const float4 v = *(const float4*)&Wp[(size_t)(r0 + lr) * C + c0 + tx * 4];
    t[lr][tx * 4 + 0] = v.x; t[lr][tx * 4 + 1] = v.y;
    t[lr][tx * 4 + 2] = v.z; t[lr][tx * 4 + 3] = v.w;
  }
  __syncthreads();
#pragma unroll
  for (int i = 0; i < 4; i++) {
    int lc = ty + i * 16;                 // output row = original col
    ushort4 o;
    o.x = f2bf(t[tx * 4 + 0][lc]);
    o.y = f2bf(t[tx * 4 + 1][lc]);
    o.z = f2bf(t[tx * 4 + 2][lc]);
    o.w = f2bf(t[tx * 4 + 3][lc]);
    *(ushort4*)&Tp[(size_t)(c0 + lc) * R + r0 + tx * 4] = o;
  }
}

// ---------------- router: fp64 scores, softmax, top-2 ------------------------
__global__ __launch_bounds__(256) void k_router(const float* __restrict__ x,
                                                const float* __restrict__ Wr,
                                                const float* __restrict__ br,
                                                const float* __restrict__ bbuf,
                                                int* cnt, int* te, float* tw) {
  int wid = threadIdx.x >> 6, lane = threadIdx.x & 63;
  int t = blockIdx.x * 4 + wid;
  const float* xp = x + (size_t)t * H_;
  double acc[E_];
#pragma unroll
  for (int e = 0; e < E_; e++) acc[e] = 0.0;
  for (int j = lane; j < H_; j += 64) {
    float xv = xp[j];
    const float4 w0 = *(const float4*)&Wr[j * 8];
    const float4 w1 = *(const float4*)&Wr[j * 8 + 4];
    acc[0] += (double)xv * (double)w0.x;
    acc[1] += (double)xv * (double)w0.y;
    acc[2] += (double)xv * (double)w0.z;
    acc[3] += (double)xv * (double)w0.w;
    acc[4] += (double)xv * (double)w1.x;
    acc[5] += (double)xv * (double)w1.y;
    acc[6] += (double)xv * (double)w1.z;
    acc[7] += (double)xv * (double)w1.w;
  }
#pragma unroll
  for (int e = 0; e < E_; e++)
    for (int s = 32; s > 0; s >>= 1) acc[e] += __shfl_xor(acc[e], s);
  if (lane == 0) {
    double s[E_], m = -1e300;
    for (int e = 0; e < E_; e++) { s[e] = acc[e] + (double)br[e]; if (s[e] > m) m = s[e]; }
    double pe[E_], sum = 0.0;
    for (int e = 0; e < E_; e++) { pe[e] = exp(s[e] - m); sum += pe[e]; }
    double pr[E_], bb[E_];
    for (int e = 0; e < E_; e++) { pr[e] = pe[e] / sum; bb[e] = pr[e] + (double)bbuf[e]; }
    int e0 = 0;
    for (int e = 1; e < E_; e++) if (bb[e] > bb[e0]) e0 = e;
    int e1 = (e0 == 0) ? 1 : 0;
    for (int e = 0; e < E_; e++) if (e != e0 && bb[e] > bb[e1]) e1 = e;
    int a0 = 0;
    for (int e = 1; e < E_; e++) if (pr[e] > pr[a0]) a0 = e;
    int a1 = (a0 == 0) ? 1 : 0;
    for (int e = 0; e < E_; e++) if (e != a0 && pr[e] > pr[a1]) a1 = e;
    double iv = 1.0 / (pr[a0] + pr[a1]);
    te[t * 2] = e0; te[t * 2 + 1] = e1;
    tw[t * 2] = (float)(pr[a0] * iv); tw[t * 2 + 1] = (float)(pr[a1] * iv);
    atomicAdd(&cnt[e0], 1); atomicAdd(&cnt[e1], 1);
  }
}

// ---------------- offsets: pad each expert's region to multiple of 128 -------
__global__ void k_offsets(const int* cnt, int* off) {
  if (threadIdx.x == 0 && blockIdx.x == 0) {
    int o = 0; off[0] = 0;
    for (int e = 0; e < E_; e++) { o += ((cnt[e] + 127) >> 7) << 7; off[e + 1] = o; }
  }
}

// ---------------- build per-expert token lists -------------------------------
__global__ void k_build(const int* __restrict__ te, const float* __restrict__ tw,
                        const int* __restrict__ off, int* cur, int* tok, float* wl) {
  int t = blockIdx.x * 256 + threadIdx.x;
  if (t >= NTOK) return;
#pragma unroll
  for (int s = 0; s < 2; s++) {
    int e = te[t * 2 + s];
    int slot = atomicAdd(&cur[e], 1);
    int pos = off[e] + slot;
    tok[pos] = t; wl[pos] = tw[t * 2 + s];
  }
}

// ---------------- gather x rows -> bf16 compacted ----------------------------
__global__ __launch_bounds__(256) void k_gather(const float* __restrict__ x,
                                                const int* __restrict__ tok,
                                                ushort* __restrict__ Xg) {
  int row = blockIdx.x;
  int t = tok[row];
  if (t < 0) return;
  const float4* src = (const float4*)(x + (size_t)t * H_);
  ushort4* dst = (ushort4*)(Xg + (size_t)row * H_);
  int i = threadIdx.x;   // 256 threads * 4 floats = 1024
  float4 v = src[i];
  ushort4 o; o.x = f2bf(v.x); o.y = f2bf(v.y); o.z = f2bf(v.z); o.w = f2bf(v.w);
  dst[i] = o;
}

// ---------------- zero output ------------------------------------------------
__global__ void k_zero(float* out) {
  size_t i = (size_t)blockIdx.x * 256 + threadIdx.x;
  float4 z; z.x = 0.f; z.y = 0.f; z.z = 0.f; z.w = 0.f;
  ((float4*)out)[i] = z;
}

// ---------------- tiled bf16 MFMA GEMM (m97-style global_load_lds staging) ---
// A [rows][K] bf16 row-major; BT [E][N][K] bf16 (k-contiguous).
// 1D grid = NT * MBLK blocks; bijective XCD swizzle + M-group-of-8 raster.
// MODE 0: C = gelu(A@B + b1[e]) -> Cbf (bf16 [rows][N])
// MODE 1: atomicAdd(Out[tok[r]][c], wl[r] * (A@B + b2[e]))
template <int MODE>
__global__ __launch_bounds__(256) void k_gemm(const ushort* __restrict__ A,
                                              const ushort* __restrict__ BT,
                                              const float* __restrict__ bias,
                                              ushort* __restrict__ Cbf,
                                              float* __restrict__ Out,
                                              const int* __restrict__ off,
                                              const int* __restrict__ tok,
                                              const float* __restrict__ wl,
                                              int K, int N, int NT) {
  // ---- block id -> (m, n): XCD-chunked swizzle, then group-of-8-M raster ----
  int nwg = gridDim.x;            // divisible by 8 (4352 or 1088)
  int cpx = nwg >> 3;
  int bid = blockIdx.x;
  int lid = (bid & 7) * cpx + (bid >> 3);
  int gsz = NT << 3;              // blocks per M-group (8 M-rows x NT)
  int g = lid / gsz, r = lid % gsz;
  int n = r >> 3;                 // N-tile (fastest within group after mi)
  int m = (g << 3) + (r & 7);
  int row0 = m * 128;
  int lastoff = off[E_];
  if (row0 >= lastoff) return;
  int e = 0;
  while (off[e + 1] <= row0) e++;
  int n0 = n * 128;
  const ushort* Bp = BT + (size_t)e * (size_t)N * (size_t)K;

  __shared__ __align__(16) ushort As[128 * 32];
  __shared__ __align__(16) ushort Bs[128 * 32];

  int tid = threadIdx.x, lane = tid & 63, wid = tid >> 6;
  int wr = wid >> 1, wc = wid & 1;

  f32x4 acc[4][4];
#pragma unroll
  for (int mm = 0; mm < 4; mm++)
#pragma unroll
    for (int nn = 0; nn < 4; nn++) acc[mm][nn] = (f32x4){0.f, 0.f, 0.f, 0.f};

  // staging: wave w covers 16 rows (1 KiB); lane l -> row w*16 + l/4, byte (l&3)*16
  int srow = (wid << 4) + (lane >> 2);   // 0..63
  int skb  = (lane & 3) << 4;            // 0/16/32/48 bytes within 64B row
  const char* aG0 = (const char*)(A  + (size_t)(row0 + srow) * K) + skb;
  const char* aG1 = (const char*)(A  + (size_t)(row0 + 64 + srow) * K) + skb;
  const char* bG0 = (const char*)(Bp + (size_t)(n0 + srow) * K) + skb;
  const char* bG1 = (const char*)(Bp + (size_t)(n0 + 64 + srow) * K) + skb;
  ushort* lA0 = As + (wid << 9);         // wid*1024 bytes
  ushort* lA1 = lA0 + 2048;              // rows 64..127
  ushort* lB0 = Bs + (wid << 9);
  ushort* lB1 = lB0 + 2048;

  int fr = lane & 15, fq = lane >> 4;    // fragment row-in-16, k-group
  int aOff0 = ((wr << 6) + fr) * 32 + (fq << 3);
  int bOff0 = ((wc << 6) + fr) * 32 + (fq << 3);

  int nk = K >> 5;
  for (int kk = 0; kk < nk; kk++) {
    size_t kb = (size_t)kk << 6;         // 32 elems * 2B per K-step
    __syncthreads();
    glds16(aG0 + kb, lA0);
    glds16(aG1 + kb, lA1);
    glds16(bG0 + kb, lB0);
    glds16(bG1 + kb, lB1);
    __syncthreads();                     // compiler drains vmcnt(0) here
    short8 af[4], bfr[4];
#pragma unroll
    for (int mm = 0; mm < 4; mm++) af[mm] = *(const short8*)&As[aOff0 + mm * 16 * 32];
#pragma unroll
    for (int nn = 0; nn < 4; nn++) bfr[nn] = *(const short8*)&Bs[bOff0 + nn * 16 * 32];
#pragma unroll
    for (int mm = 0; mm < 4; mm++)
#pragma unroll
      for (int nn = 0; nn < 4; nn++)
        acc[mm][nn] = __builtin_amdgcn_mfma_f32_16x16x32_bf16(af[mm], bfr[nn], acc[mm][nn], 0, 0, 0);
  }

  const float* bp = bias + (size_t)e * N;
  if (MODE == 0) {
#pragma unroll
    for (int mm = 0; mm < 4; mm++)
#pragma unroll
      for (int nn = 0; nn < 4; nn++)
#pragma unroll
        for (int j = 0; j < 4; j++) {
          int rr = row0 + (wr << 6) + mm * 16 + (fq << 2) + j;
          int c = n0 + (wc << 6) + nn * 16 + fr;
          float v = acc[mm][nn][j] + bp[c];
          v = 0.5f * v * (1.0f + erff(v * 0.70710678118654752f));
          Cbf[(size_t)rr * (size_t)N + c] = f2bf(v);
        }
  } else {
#pragma unroll
    for (int mm = 0; mm < 4; mm++)
#pragma unroll
      for (int j = 0; j < 4; j++) {
        int rr = row0 + (wr << 6) + mm * 16 + (fq << 2) + j;
        int t = tok[rr];
        if (t < 0) continue;
        float w = wl[rr];
#pragma unroll
        for (int nn = 0; nn < 4; nn++) {
          int c = n0 + (wc << 6) + nn * 16 + fr;
          atomicAdd(&Out[(size_t)t * (size_t)N + c], w * (acc[mm][nn][j] + bp[c]));
        }
      }
  }
}

extern "C" void kernel_launch(void* const* d_in, const int* in_sizes, int n_in,
                              void* d_out, int out_size, void* d_ws, size_t ws_size,
                              hipStream_t stream) {
  (void)in_sizes; (void)n_in; (void)out_size; (void)ws_size;
  const float* x    = (const float*)d_in[0];
  const float* bbuf = (const float*)d_in[1];
  const float* Wr   = (const float*)d_in[2];
  const float* br   = (const float*)d_in[3];
  const float* W1   = (const float*)d_in[4];
  const float* b1   = (const float*)d_in[5];
  const float* W2   = (const float*)d_in[6];
  const float* b2   = (const float*)d_in[7];
  float* out = (float*)d_out;

  char* ws = (char*)d_ws;
  ushort* W1T = (ushort*)ws;                         // [E][F][H] bf16: 67108864 B
  ushort* W2T = (ushort*)(ws + 67108864);            // [E][H][F] bf16: 67108864 B
  ushort* Xg  = (ushort*)(ws + 134217728);           // [ROWS_CAP][H] bf16
  ushort* h1  = (ushort*)(ws + 169869312);           // [ROWS_CAP][F] bf16
  char* meta  = ws + 312475648;
  int*   cnt = (int*)(meta);
  int*   off = (int*)(meta + 64);
  int*   cur = (int*)(meta + 128);
  int*   te  = (int*)(meta + 256);                   // [NTOK*2]
  float* tw  = (float*)(meta + 256 + 65536);         // [NTOK*2]
  int*   tok = (int*)(meta + 256 + 131072);          // [ROWS_CAP]
  float* wl  = (float*)(meta + 256 + 131072 + 69632);// [ROWS_CAP]

  k_init<<<ROWS_CAP / 256, 256, 0, stream>>>(cnt, cur, tok, wl);
  k_transcvt<<<dim3(F_ / 64, H_ / 64, E_), 256, 0, stream>>>(W1, W1T, H_, F_);
  k_transcvt<<<dim3(H_ / 64, F_ / 64, E_), 256, 0, stream>>>(W2, W2T, F_, H_);
  k_router<<<NTOK / 4, 256, 0, stream>>>(x, Wr, br, bbuf, cnt, te, tw);
  k_offsets<<<1, 64, 0, stream>>>(cnt, off);
  k_build<<<NTOK / 256, 256, 0, stream>>>(te, tw, off, cur, tok, wl);
  k_gather<<<ROWS_CAP, 256, 0, stream>>>(x, tok, Xg);
  k_zero<<<(NTOK * H_ / 4) / 256, 256, 0, stream>>>(out);
  k_gemm<0><<<32 * MBLK, 256, 0, stream>>>(Xg, W1T, b1, h1, nullptr, off, nullptr, nullptr, H_, F_, 32);
  k_gemm<1><<<8 * MBLK, 256, 0, stream>>>(h1, W2T, b2, nullptr, out, off, tok, wl, F_, H_, 8);
}